// Round 5
// baseline (274.975 us; speedup 1.0000x reference)
//
#include <hip/hip_runtime.h>
#include <hip/hip_bf16.h>
#include <stdint.h>

// Problem: B=4, S=2048, D=1024. fp32 in, fp32 out.
#define BB 4
#define SS 2048
#define DD 1024

typedef __attribute__((ext_vector_type(4))) float f32x4;
typedef __attribute__((ext_vector_type(8))) __bf16 bf16x8;

typedef const __attribute__((address_space(1))) void* gptr_t;
typedef __attribute__((address_space(3))) void* lptr_t;

__device__ __forceinline__ void load_lds16(const void* g, void* l) {
  // async global->LDS, 16B per lane; LDS dest = wave-uniform base + lane*16
  __builtin_amdgcn_global_load_lds((gptr_t)g, (lptr_t)l, 16, 0, 0);
}

#define SBAR0() __builtin_amdgcn_sched_barrier(0)

template <int N>
__device__ __forceinline__ void wait_vmcnt() {
  if constexpr (N == 0) asm volatile("s_waitcnt vmcnt(0)" ::: "memory");
  else if constexpr (N == 3) asm volatile("s_waitcnt vmcnt(3)" ::: "memory");
  else if constexpr (N == 4) asm volatile("s_waitcnt vmcnt(4)" ::: "memory");
  else if constexpr (N == 6) asm volatile("s_waitcnt vmcnt(6)" ::: "memory");
  else if constexpr (N == 8) asm volatile("s_waitcnt vmcnt(8)" ::: "memory");
}
__device__ __forceinline__ void wait_lgkm0() {
  asm volatile("s_waitcnt lgkmcnt(0)" ::: "memory");
}

__device__ __forceinline__ unsigned short f2bf(float x) {
  union { float f; uint32_t u; } v; v.f = x;
  uint32_t u = v.u;
  return (unsigned short)((u + 0x7FFFu + ((u >> 16) & 1u)) >> 16); // RNE
}
__device__ __forceinline__ float bf2f(unsigned short h) {
  union { uint32_t u; float f; } v; v.u = ((uint32_t)h) << 16; return v.f;
}

// ---------------- fp32 -> bf16 convert: x (grid-stride) ----------------
__global__ __launch_bounds__(256) void convert_x(
    const float* __restrict__ in, unsigned short* __restrict__ out, int n4) {
  for (int i = blockIdx.x * 256 + threadIdx.x; i < n4; i += gridDim.x * 256) {
    float4 v = ((const float4*)in)[i];
    ushort4 o;
    o.x = f2bf(v.x); o.y = f2bf(v.y); o.z = f2bf(v.z); o.w = f2bf(v.w);
    ((ushort4*)out)[i] = o;
  }
}

// ---------------- fp32 -> bf16 convert: the 3 weight matrices ----------------
__global__ __launch_bounds__(256) void convert_w(
    const float* __restrict__ wq, const float* __restrict__ wk,
    const float* __restrict__ wv, unsigned short* __restrict__ wcat) {
  const int n4 = DD * DD / 4;  // per matrix
  int i = blockIdx.x * 256 + threadIdx.x;  // 0 .. 3*n4-1
  const int which = i / n4, j = i - which * n4;
  const float* src = (which == 0) ? wq : ((which == 1) ? wk : wv);
  float4 v = ((const float4*)src)[j];
  ushort4 o;
  o.x = f2bf(v.x); o.y = f2bf(v.y); o.z = f2bf(v.z); o.w = f2bf(v.w);
  ((ushort4*)(wcat + (size_t)which * DD * DD))[j] = o;
}

// =============== phase-interleaved GEMM core (T3+T4 schedule) ===============
// C[BM x 256] = A[M,K] @ Bt[N,K]^T, bf16 MFMA 16x16x32, 512 thr = 8 waves (2x4).
// BK=32 subtiles in a 4-deep LDS ring (A: 4 x BM*64B, B: 4 x 16KB).
// Per subtile k: boundary {counted vmcnt, barrier}; then per phase:
// {ds_read frags | issue stage for subtile k+3 | lgkm0 | 16 MFMA under setprio}.
// Steady-state vmcnt(2*LPS) retires exactly subtile k; loads for k+1,k+2 stay
// in flight across barriers (never drain to 0 mid-loop).
// T2 swizzle on 64B subtile rows: phys col16 = logical ^ (row&3), applied
// BOTH sides (pre-swizzled global source + swizzled ds_read addr, rule #21).
template <int BM, int KLEN>
__device__ __forceinline__ void gemm_core(
    const unsigned short* __restrict__ A, const unsigned short* __restrict__ Bt,
    int lda, int ldb, int row0, int col0, char* lds,
    f32x4 (&acc)[BM / 32][4]) {
  constexpr int M_REP = BM / 32;        // 4 or 8
  constexpr int NT   = KLEN / 32;       // subtiles
  constexpr int RA   = BM / 128;        // A stage rounds (1 or 2)
  constexpr int LPS  = RA + 2;          // loads per thread per subtile
  constexpr int ASUB = BM * 64;         // A subtile bytes
  constexpr int BSUB = 16384;           // B subtile bytes (256 x 32 x 2B)

  const int tid = threadIdx.x, lane = tid & 63, w = tid >> 6;
  const int wr = w >> 2, wc = w & 3;    // 2 x 4 wave grid

#pragma unroll
  for (int m = 0; m < M_REP; ++m)
#pragma unroll
    for (int n = 0; n < 4; ++n) acc[m][n] = (f32x4)(0.f);

  // ---- stage-side addressing: thread T covers row T>>2, source col16
  //      pre-swizzled so linear LDS write realizes phys = logical^(row&3) ----
  const int arow = tid >> 2;
  const int acol = (tid & 3) ^ ((tid >> 2) & 3);
  const unsigned short* srcA = A  + (size_t)(row0 + arow) * lda + acol * 8;
  const unsigned short* srcB = Bt + (size_t)(col0 + arow) * ldb + acol * 8;

  // ---- read-side addressing (swizzled): row = base + (lane&15), logical
  //      col16 = lane>>4  ->  phys col16 = (lane>>4) ^ (lane&3) ----
  const int xcol = ((lane >> 4) ^ (lane & 3)) * 16;
  const char* rdA = lds + (wr * (BM / 2) + (lane & 15)) * 64 + xcol;
  const char* rdB = lds + 4 * ASUB + (wc * 64 + (lane & 15)) * 64 + xcol;

  auto STAGE_A = [&](int k) {
    char* d = lds + (k & 3) * ASUB + w * 1024;
    const unsigned short* s = srcA + k * 32;
#pragma unroll
    for (int r = 0; r < RA; ++r)
      load_lds16(s + (size_t)r * 128 * lda, d + r * 8192);
  };
  auto STAGE_B = [&](int k) {
    char* d = lds + 4 * ASUB + (k & 3) * BSUB + w * 1024;
    const unsigned short* s = srcB + k * 32;
#pragma unroll
    for (int r = 0; r < 2; ++r)
      load_lds16(s + (size_t)r * 128 * ldb, d + r * 8192);
  };

  STAGE_A(0); STAGE_B(0);
  STAGE_A(1); STAGE_B(1);
  STAGE_A(2); STAGE_B(2);

#pragma unroll 1
  for (int k = 0; k < NT; ++k) {
    // ---- boundary: subtile k must be landed; k+1,k+2 stay in flight ----
    if (k + 2 < NT) wait_vmcnt<2 * LPS>();
    else if (k + 1 < NT) wait_vmcnt<LPS>();
    else wait_vmcnt<0>();
    SBAR0();
    __builtin_amdgcn_s_barrier();
    SBAR0();

    const char* pA = rdA + (k & 3) * ASUB;
    const char* pB = rdB + (k & 3) * BSUB;

    // ---- phase 1: frags (a0..3, b0..3), stage A (+B if BM==128), MFMA ----
    bf16x8 bf[4], af[4];
#pragma unroll
    for (int n = 0; n < 4; ++n) bf[n] = *(const bf16x8*)(pB + n * 1024);
#pragma unroll
    for (int m = 0; m < 4; ++m) af[m] = *(const bf16x8*)(pA + m * 1024);
    if (k + 3 < NT) {
      STAGE_A(k + 3);
      if constexpr (M_REP == 4) STAGE_B(k + 3);
    }
    wait_lgkm0();
    SBAR0();
    __builtin_amdgcn_s_setprio(1);
#pragma unroll
    for (int m = 0; m < 4; ++m)
#pragma unroll
      for (int n = 0; n < 4; ++n)
        acc[m][n] = __builtin_amdgcn_mfma_f32_16x16x32_bf16(af[m], bf[n], acc[m][n], 0, 0, 0);
    __builtin_amdgcn_s_setprio(0);

    // ---- phase 2 (BM==256): frags a4..7, stage B, MFMA ----
    if constexpr (M_REP == 8) {
      bf16x8 ag[4];
#pragma unroll
      for (int m = 0; m < 4; ++m) ag[m] = *(const bf16x8*)(pA + (4 + m) * 1024);
      if (k + 3 < NT) STAGE_B(k + 3);
      wait_lgkm0();
      SBAR0();
      __builtin_amdgcn_s_setprio(1);
#pragma unroll
      for (int m = 0; m < 4; ++m)
#pragma unroll
        for (int n = 0; n < 4; ++n)
          acc[4 + m][n] = __builtin_amdgcn_mfma_f32_16x16x32_bf16(ag[m], bf[n], acc[4 + m][n], 0, 0, 0);
      __builtin_amdgcn_s_setprio(0);
    }
  }
}

// ---------------- projection GEMM: [8192,1024] @ Wcat[3072,1024]^T ----------
// BM=128, BN=256: grid 12 x 64 = 768 blocks (3 exact GPU rounds).
__global__ __launch_bounds__(512, 2) void proj_gemm(
    const unsigned short* __restrict__ xb, const unsigned short* __restrict__ wcat,
    unsigned short* __restrict__ q, unsigned short* __restrict__ kk,
    unsigned short* __restrict__ vv) {
  extern __shared__ char lds[];
  f32x4 acc[4][4];
  const int bn = blockIdx.x, bm = blockIdx.y;
  gemm_core<128, 1024>(xb, wcat, 1024, 1024, bm * 128, bn * 256, lds, acc);

  const int lane = threadIdx.x & 63, w = threadIdx.x >> 6;
  const int wr = w >> 2, wc = w & 3;
  const int which = bn >> 2;  // 0:q 1:k 2:v
  unsigned short* dst = (which == 0) ? q : ((which == 1) ? kk : vv);
  const int colb = (bn & 3) * 256 + wc * 64 + (lane & 15);
  const int rowb = bm * 128 + wr * 64 + (lane >> 4) * 4;
#pragma unroll
  for (int f = 0; f < 4; ++f)
#pragma unroll
    for (int i = 0; i < 4; ++i) {
      const size_t rowoff = (size_t)(rowb + f * 16 + i) * 1024;
#pragma unroll
      for (int n = 0; n < 4; ++n)
        dst[rowoff + colb + n * 16] = f2bf(acc[f][n][i]);
    }
}

// ---------------- K -> Mt (reshape folded transpose) ----------------
// Mt[b][delta*1024 + j][i] = K[b][2i+delta][j]
__global__ __launch_bounds__(256) void k_to_mt(
    const unsigned short* __restrict__ k, unsigned short* __restrict__ mt) {
  const int z = blockIdx.z, b = z >> 1, delta = z & 1;
  const unsigned short* kb = k + (size_t)b * SS * DD + (size_t)delta * DD;  // ld=2048
  unsigned short* mtb = mt + (size_t)b * SS * DD + (size_t)delta * DD * DD; // [1024][1024]
  __shared__ unsigned short tile[32][33];
  const int tx = threadIdx.x, ty = threadIdx.y;
  const int i0 = blockIdx.x * 32, j0 = blockIdx.y * 32;
#pragma unroll
  for (int yy = ty; yy < 32; yy += 8)
    tile[yy][tx] = kb[(size_t)(i0 + yy) * 2048 + j0 + tx];
  __syncthreads();
#pragma unroll
  for (int yy = ty; yy < 32; yy += 8)
    mtb[(size_t)(j0 + yy) * 1024 + i0 + tx] = tile[tx][yy];
}

// ---------------- V -> Vt ----------------
__global__ __launch_bounds__(256) void v_to_vt(
    const unsigned short* __restrict__ v, unsigned short* __restrict__ vt) {
  const int b = blockIdx.z;
  const unsigned short* vb = v + (size_t)b * SS * DD;   // V[k][n], ld=1024
  unsigned short* vtb = vt + (size_t)b * DD * SS;       // Vt[n][k], ld=2048
  __shared__ unsigned short tile[32][33];
  const int tx = threadIdx.x, ty = threadIdx.y;
  const int k0 = blockIdx.x * 32, n0 = blockIdx.y * 32;
#pragma unroll
  for (int yy = ty; yy < 32; yy += 8)
    tile[yy][tx] = vb[(size_t)(k0 + yy) * 1024 + n0 + tx];
  __syncthreads();
#pragma unroll
  for (int yy = ty; yy < 32; yy += 8)
    vtb[(size_t)(n0 + yy) * 2048 + k0 + tx] = tile[tx][yy];
}

// ---------------- scores GEMM: Q[2048,1024] @ Mt[2048,1024]^T (x 1/1024) ----
// BM=256: grid 8 x 8 x 4 = 256 blocks (1 exact GPU round).
__global__ __launch_bounds__(512, 2) void score_gemm(
    const unsigned short* __restrict__ q, const unsigned short* __restrict__ mt,
    unsigned short* __restrict__ sc) {
  extern __shared__ char lds[];
  f32x4 acc[8][4];
  const int b = blockIdx.z;
  gemm_core<256, 1024>(q + (size_t)b * SS * DD, mt + (size_t)b * SS * DD,
                       1024, 1024, blockIdx.y * 256, blockIdx.x * 256, lds, acc);
  unsigned short* out = sc + (size_t)b * SS * SS;
  const int lane = threadIdx.x & 63, w = threadIdx.x >> 6;
  const int wr = w >> 2, wc = w & 3;
  const int colb = blockIdx.x * 256 + wc * 64 + (lane & 15);
  const int rowb = blockIdx.y * 256 + wr * 128 + (lane >> 4) * 4;
  const float scale = 1.0f / 1024.0f;
#pragma unroll
  for (int f = 0; f < 8; ++f)
#pragma unroll
    for (int i = 0; i < 4; ++i) {
      const size_t rowoff = (size_t)(rowb + f * 16 + i) * 2048;
#pragma unroll
      for (int n = 0; n < 4; ++n)
        out[rowoff + colb + n * 16] = f2bf(acc[f][n][i] * scale);
    }
}

// ---------------- row softmax IN-PLACE: bf16 [8192][2048] ----------------
__global__ __launch_bounds__(256) void softmax_kernel(unsigned short* __restrict__ sc) {
  const size_t row = blockIdx.x;
  unsigned short* io = sc + row * 2048;
  const int t = threadIdx.x;
  ushort4 u0 = ((const ushort4*)io)[t];
  ushort4 u1 = ((const ushort4*)io)[t + 256];
  float v[8];
  v[0] = bf2f(u0.x); v[1] = bf2f(u0.y); v[2] = bf2f(u0.z); v[3] = bf2f(u0.w);
  v[4] = bf2f(u1.x); v[5] = bf2f(u1.y); v[6] = bf2f(u1.z); v[7] = bf2f(u1.w);
  float m = v[0];
#pragma unroll
  for (int j = 1; j < 8; ++j) m = fmaxf(m, v[j]);
#pragma unroll
  for (int off = 32; off > 0; off >>= 1) m = fmaxf(m, __shfl_xor(m, off));
  __shared__ float redm[4], reds[4];
  const int w = t >> 6;
  if ((t & 63) == 0) redm[w] = m;
  __syncthreads();
  m = fmaxf(fmaxf(redm[0], redm[1]), fmaxf(redm[2], redm[3]));
  float s = 0.f;
#pragma unroll
  for (int j = 0; j < 8; ++j) { v[j] = __expf(v[j] - m); s += v[j]; }
#pragma unroll
  for (int off = 32; off > 0; off >>= 1) s += __shfl_xor(s, off);
  if ((t & 63) == 0) reds[w] = s;
  __syncthreads();
  const float inv = 1.0f / (reds[0] + reds[1] + reds[2] + reds[3]);
  ushort4 o0, o1;
  o0.x = f2bf(v[0] * inv); o0.y = f2bf(v[1] * inv); o0.z = f2bf(v[2] * inv); o0.w = f2bf(v[3] * inv);
  o1.x = f2bf(v[4] * inv); o1.y = f2bf(v[5] * inv); o1.z = f2bf(v[6] * inv); o1.w = f2bf(v[7] * inv);
  ((ushort4*)io)[t] = o0;
  ((ushort4*)io)[t + 256] = o1;
}

// ---------------- PV GEMM: P[2048,2048] @ Vt[1024,2048]^T -> fp32 ----------
// BM=128: grid 4 x 16 x 4 = 256 blocks (1 exact GPU round).
__global__ __launch_bounds__(512, 2) void pv_gemm(
    const unsigned short* __restrict__ p, const unsigned short* __restrict__ vt,
    float* __restrict__ out) {
  extern __shared__ char lds[];
  f32x4 acc[4][4];
  const int b = blockIdx.z;
  gemm_core<128, 2048>(p + (size_t)b * SS * SS, vt + (size_t)b * DD * SS,
                       2048, 2048, blockIdx.y * 128, blockIdx.x * 256, lds, acc);
  float* ob = out + (size_t)b * SS * DD;
  const int lane = threadIdx.x & 63, w = threadIdx.x >> 6;
  const int wr = w >> 2, wc = w & 3;
  const int colb = blockIdx.x * 256 + wc * 64 + (lane & 15);
  const int rowb = blockIdx.y * 128 + wr * 64 + (lane >> 4) * 4;
#pragma unroll
  for (int f = 0; f < 4; ++f)
#pragma unroll
    for (int i = 0; i < 4; ++i) {
      const size_t rowoff = (size_t)(rowb + f * 16 + i) * 1024;
#pragma unroll
      for (int n = 0; n < 4; ++n)
        ob[rowoff + colb + n * 16] = acc[f][n][i];
    }
}

extern "C" void kernel_launch(void* const* d_in, const int* in_sizes, int n_in,
                              void* d_out, int out_size, void* d_ws, size_t ws_size,
                              hipStream_t stream) {
  const float* x  = (const float*)d_in[0];
  const float* wq = (const float*)d_in[1];
  const float* wk = (const float*)d_in[2];
  const float* wv = (const float*)d_in[3];
  float* out = (float*)d_out;
  uint8_t* ws = (uint8_t*)d_ws;

  const size_t MB = 1u << 20;
  unsigned short* xb   = (unsigned short*)(ws);               // 16 MB  [8192][1024]
  unsigned short* wcat = (unsigned short*)(ws + 16 * MB);     //  6 MB  [3072][1024]
  unsigned short* q    = (unsigned short*)(ws + 22 * MB);     // 16 MB
  unsigned short* kk   = (unsigned short*)(ws + 38 * MB);     // 16 MB
  unsigned short* vv   = (unsigned short*)(ws + 54 * MB);     // 16 MB
  unsigned short* mt   = (unsigned short*)(ws + 70 * MB);     // 16 MB  [b][2048][1024]
  unsigned short* vt   = (unsigned short*)(ws + 86 * MB);     // 16 MB  [b][1024][2048]
  unsigned short* sc   = (unsigned short*)(ws + 102 * MB);    // 32 MB  [b][2048][2048] (softmax in-place)
                                                              // -> 134 MB total

  convert_x<<<2048, 256, 0, stream>>>(x, xb, BB * SS * DD / 4);
  convert_w<<<3 * DD * DD / 4 / 256, 256, 0, stream>>>(wq, wk, wv, wcat);
  proj_gemm<<<dim3(12, 64), 512, 96 * 1024, stream>>>(xb, wcat, q, kk, vv);
  k_to_mt<<<dim3(32, 32, 8), dim3(32, 8), 0, stream>>>(kk, mt);
  v_to_vt<<<dim3(64, 32, 4), dim3(32, 8), 0, stream>>>(vv, vt);
  score_gemm<<<dim3(8, 8, 4), 512, 128 * 1024, stream>>>(q, mt, sc);
  softmax_kernel<<<BB * SS, 256, 0, stream>>>(sc);
  pv_gemm<<<dim3(4, 16, 4), 512, 96 * 1024, stream>>>(sc, vt, out);
}

// Round 6
// 264.701 us; speedup vs baseline: 1.0388x; 1.0388x over previous
//
#include <hip/hip_runtime.h>
#include <hip/hip_bf16.h>
#include <stdint.h>

// Problem: B=4, S=2048, D=1024. fp32 in, fp32 out.
#define BB 4
#define SS 2048
#define DD 1024

typedef __attribute__((ext_vector_type(4))) float f32x4;
typedef __attribute__((ext_vector_type(8))) __bf16 bf16x8;

typedef const __attribute__((address_space(1))) void* gptr_t;
typedef __attribute__((address_space(3))) void* lptr_t;

__device__ __forceinline__ void load_lds16(const void* g, void* l) {
  // async global->LDS, 16B per lane; LDS dest = wave-uniform base + lane*16
  __builtin_amdgcn_global_load_lds((gptr_t)g, (lptr_t)l, 16, 0, 0);
}

#define SBAR0() __builtin_amdgcn_sched_barrier(0)

__device__ __forceinline__ void wait_vm0() {
  asm volatile("s_waitcnt vmcnt(0)" ::: "memory");
}
__device__ __forceinline__ void wait_lgkm0() {
  asm volatile("s_waitcnt lgkmcnt(0)" ::: "memory");
}

__device__ __forceinline__ unsigned short f2bf(float x) {
  union { float f; uint32_t u; } v; v.f = x;
  uint32_t u = v.u;
  return (unsigned short)((u + 0x7FFFu + ((u >> 16) & 1u)) >> 16); // RNE
}
__device__ __forceinline__ float bf2f(unsigned short h) {
  union { uint32_t u; float f; } v; v.u = ((uint32_t)h) << 16; return v.f;
}

// ---------------- fp32 -> bf16 convert: x (grid-stride) ----------------
__global__ __launch_bounds__(256) void convert_x(
    const float* __restrict__ in, unsigned short* __restrict__ out, int n4) {
  for (int i = blockIdx.x * 256 + threadIdx.x; i < n4; i += gridDim.x * 256) {
    float4 v = ((const float4*)in)[i];
    ushort4 o;
    o.x = f2bf(v.x); o.y = f2bf(v.y); o.z = f2bf(v.z); o.w = f2bf(v.w);
    ((ushort4*)out)[i] = o;
  }
}

// ---------------- fp32 -> bf16 convert: the 3 weight matrices ----------------
__global__ __launch_bounds__(256) void convert_w(
    const float* __restrict__ wq, const float* __restrict__ wk,
    const float* __restrict__ wv, unsigned short* __restrict__ wcat) {
  const int n4 = DD * DD / 4;  // per matrix
  int i = blockIdx.x * 256 + threadIdx.x;  // 0 .. 3*n4-1
  const int which = i / n4, j = i - which * n4;
  const float* src = (which == 0) ? wq : ((which == 1) ? wk : wv);
  float4 v = ((const float4*)src)[j];
  ushort4 o;
  o.x = f2bf(v.x); o.y = f2bf(v.y); o.z = f2bf(v.z); o.w = f2bf(v.w);
  ((ushort4*)(wcat + (size_t)which * DD * DD))[j] = o;
}

// ============ phase-interleaved GEMM core (m201-style schedule) ============
// C[BM x 256] = A[M,K] @ Bt[N,K]^T, bf16 MFMA 16x16x32, 512 thr = 8 waves
// (2 M x 4 N), wave tile (BM/2) x 64. BK=64, double-buffered LDS with the
// round-4 PROVEN layout (128B rows, phys col16 = logical ^ (row&7), both
// sides, 0 bank conflicts on HW).
// Per K-tile: entry {vmcnt(0); barrier} (loads were issued a full tile ago ->
// ~zero residual), then 4 phases (BM=256) / 2 phases (BM=128), each:
// {ds_read frag subtile; [phase0: burst-stage tile t+1 into dead buffer];
//  barrier; lgkmcnt(0); setprio(1); 16 MFMA; setprio(0); barrier}.
// Stage writes only ever target buffer (t+1)&1 whose readers finished before
// tile t's entry barrier -> race-free by construction; loads stay in flight
// across all intra-tile barriers (T4 mechanism, trivial ledger).
template <int BM, int KLEN>
__device__ __forceinline__ void gemm_core8(
    const unsigned short* __restrict__ A, const unsigned short* __restrict__ Bt,
    int lda, int ldb, int row0, int col0, char* lds,
    f32x4 (&acc)[BM / 32][4]) {
  constexpr int M_REP = BM / 32;        // 4 or 8
  constexpr int NT   = KLEN / 64;       // K tiles
  constexpr int ASZ  = BM * 128;        // A bytes per buffer
  constexpr int BUF  = ASZ + 32768;     // + B (256 x 64 x 2B)
  constexpr int NCA  = BM / 64;         // A 1KB-chunks per wave

  const int tid = threadIdx.x, lane = tid & 63, w = tid >> 6;
  const int wr = w >> 2, wc = w & 3;
  const int l8 = lane >> 3, l7 = lane & 7, l15 = lane & 15, l16 = lane >> 4;

#pragma unroll
  for (int m = 0; m < M_REP; ++m)
#pragma unroll
    for (int n = 0; n < 4; ++n) acc[m][n] = (f32x4)(0.f);

  // stage-side: wave w owns 8-row chunks {w+8j}; source col16 pre-swizzled
  const unsigned short* srcA = A  + (size_t)(row0 + w * 8 + l8) * lda + (l7 ^ l8) * 8;
  const unsigned short* srcB = Bt + (size_t)(col0 + w * 8 + l8) * ldb + (l7 ^ l8) * 8;

  // read-side (swizzled): phys col16 = logical ^ (row&7), row&7 == lane&7
  const int xc0 = (l16 ^ l7) * 16;        // k-substep 0
  const int xc1 = ((4 + l16) ^ l7) * 16;  // k-substep 1
  const int rdAo = (wr * (BM / 2) + l15) * 128;
  const int rdBo = ASZ + (wc * 64 + l15) * 128;

  auto STAGE = [&](int t) {
    char* ab = lds + (t & 1) * BUF + w * 1024;
    char* bb = lds + (t & 1) * BUF + ASZ + w * 1024;
    const unsigned short* a = srcA + t * 64;
    const unsigned short* b = srcB + t * 64;
#pragma unroll
    for (int j = 0; j < NCA; ++j) load_lds16(a + (size_t)j * 64 * lda, ab + j * 8192);
#pragma unroll
    for (int j = 0; j < 4; ++j)  load_lds16(b + (size_t)j * 64 * ldb, bb + j * 8192);
  };

  STAGE(0);

#pragma unroll 1
  for (int t = 0; t < NT; ++t) {
    // ---- tile entry: my loads landed; barrier -> everyone's landed ----
    wait_vm0();
    SBAR0();
    __builtin_amdgcn_s_barrier();
    SBAR0();
    const char* pA = lds + (t & 1) * BUF + rdAo;
    const char* pB = lds + (t & 1) * BUF + rdBo;

    bf16x8 bfr[4], afr[4];
    // ---- phase 0: s=0, m 0..3 (+ burst-stage tile t+1) ----
#pragma unroll
    for (int n = 0; n < 4; ++n) bfr[n] = *(const bf16x8*)(pB + xc0 + n * 2048);
#pragma unroll
    for (int m = 0; m < 4; ++m) afr[m] = *(const bf16x8*)(pA + xc0 + m * 2048);
    if (t + 1 < NT) STAGE(t + 1);
    SBAR0();
    __builtin_amdgcn_s_barrier();
    wait_lgkm0();
    SBAR0();
    __builtin_amdgcn_s_setprio(1);
#pragma unroll
    for (int m = 0; m < 4; ++m)
#pragma unroll
      for (int n = 0; n < 4; ++n)
        acc[m][n] = __builtin_amdgcn_mfma_f32_16x16x32_bf16(afr[m], bfr[n], acc[m][n], 0, 0, 0);
    __builtin_amdgcn_s_setprio(0);
    __builtin_amdgcn_s_barrier();

    if constexpr (M_REP == 8) {
      // ---- phase 1: s=0, m 4..7 ----
#pragma unroll
      for (int m = 0; m < 4; ++m) afr[m] = *(const bf16x8*)(pA + xc0 + (4 + m) * 2048);
      SBAR0();
      __builtin_amdgcn_s_barrier();
      wait_lgkm0();
      SBAR0();
      __builtin_amdgcn_s_setprio(1);
#pragma unroll
      for (int m = 0; m < 4; ++m)
#pragma unroll
        for (int n = 0; n < 4; ++n)
          acc[4 + m][n] = __builtin_amdgcn_mfma_f32_16x16x32_bf16(afr[m], bfr[n], acc[4 + m][n], 0, 0, 0);
      __builtin_amdgcn_s_setprio(0);
      __builtin_amdgcn_s_barrier();
    }

    // ---- phase 2: s=1, m 0..3 ----
#pragma unroll
    for (int n = 0; n < 4; ++n) bfr[n] = *(const bf16x8*)(pB + xc1 + n * 2048);
#pragma unroll
    for (int m = 0; m < 4; ++m) afr[m] = *(const bf16x8*)(pA + xc1 + m * 2048);
    SBAR0();
    __builtin_amdgcn_s_barrier();
    wait_lgkm0();
    SBAR0();
    __builtin_amdgcn_s_setprio(1);
#pragma unroll
    for (int m = 0; m < 4; ++m)
#pragma unroll
      for (int n = 0; n < 4; ++n)
        acc[m][n] = __builtin_amdgcn_mfma_f32_16x16x32_bf16(afr[m], bfr[n], acc[m][n], 0, 0, 0);
    __builtin_amdgcn_s_setprio(0);

    if constexpr (M_REP == 8) {
      __builtin_amdgcn_s_barrier();
      // ---- phase 3: s=1, m 4..7 ----
#pragma unroll
      for (int m = 0; m < 4; ++m) afr[m] = *(const bf16x8*)(pA + xc1 + (4 + m) * 2048);
      SBAR0();
      __builtin_amdgcn_s_barrier();
      wait_lgkm0();
      SBAR0();
      __builtin_amdgcn_s_setprio(1);
#pragma unroll
      for (int m = 0; m < 4; ++m)
#pragma unroll
        for (int n = 0; n < 4; ++n)
          acc[4 + m][n] = __builtin_amdgcn_mfma_f32_16x16x32_bf16(afr[m], bfr[n], acc[4 + m][n], 0, 0, 0);
      __builtin_amdgcn_s_setprio(0);
    }
    // no trailing barrier: next tile's entry {vmcnt(0); barrier} subsumes it
  }
}

// ---------------- projection GEMM: [8192,1024] @ Wcat[3072,1024]^T ----------
// BM=128, BN=256: grid 12 x 64 = 768 blocks (3 exact GPU rounds).
__global__ __launch_bounds__(512, 2) void proj_gemm(
    const unsigned short* __restrict__ xb, const unsigned short* __restrict__ wcat,
    unsigned short* __restrict__ q, unsigned short* __restrict__ kk,
    unsigned short* __restrict__ vv) {
  extern __shared__ char lds[];
  f32x4 acc[4][4];
  const int bn = blockIdx.x, bm = blockIdx.y;
  gemm_core8<128, 1024>(xb, wcat, 1024, 1024, bm * 128, bn * 256, lds, acc);

  const int lane = threadIdx.x & 63, w = threadIdx.x >> 6;
  const int wr = w >> 2, wc = w & 3;
  const int which = bn >> 2;  // 0:q 1:k 2:v
  unsigned short* dst = (which == 0) ? q : ((which == 1) ? kk : vv);
  const int colb = (bn & 3) * 256 + wc * 64 + (lane & 15);
  const int rowb = bm * 128 + wr * 64 + (lane >> 4) * 4;
#pragma unroll
  for (int f = 0; f < 4; ++f)
#pragma unroll
    for (int i = 0; i < 4; ++i) {
      const size_t rowoff = (size_t)(rowb + f * 16 + i) * 1024;
#pragma unroll
      for (int n = 0; n < 4; ++n)
        dst[rowoff + colb + n * 16] = f2bf(acc[f][n][i]);
    }
}

// ---------------- K -> Mt (reshape folded transpose) ----------------
// Mt[b][delta*1024 + j][i] = K[b][2i+delta][j]
__global__ __launch_bounds__(256) void k_to_mt(
    const unsigned short* __restrict__ k, unsigned short* __restrict__ mt) {
  const int z = blockIdx.z, b = z >> 1, delta = z & 1;
  const unsigned short* kb = k + (size_t)b * SS * DD + (size_t)delta * DD;  // ld=2048
  unsigned short* mtb = mt + (size_t)b * SS * DD + (size_t)delta * DD * DD; // [1024][1024]
  __shared__ unsigned short tile[32][33];
  const int tx = threadIdx.x, ty = threadIdx.y;
  const int i0 = blockIdx.x * 32, j0 = blockIdx.y * 32;
#pragma unroll
  for (int yy = ty; yy < 32; yy += 8)
    tile[yy][tx] = kb[(size_t)(i0 + yy) * 2048 + j0 + tx];
  __syncthreads();
#pragma unroll
  for (int yy = ty; yy < 32; yy += 8)
    mtb[(size_t)(j0 + yy) * 1024 + i0 + tx] = tile[tx][yy];
}

// ---------------- V -> Vt ----------------
__global__ __launch_bounds__(256) void v_to_vt(
    const unsigned short* __restrict__ v, unsigned short* __restrict__ vt) {
  const int b = blockIdx.z;
  const unsigned short* vb = v + (size_t)b * SS * DD;   // V[k][n], ld=1024
  unsigned short* vtb = vt + (size_t)b * DD * SS;       // Vt[n][k], ld=2048
  __shared__ unsigned short tile[32][33];
  const int tx = threadIdx.x, ty = threadIdx.y;
  const int k0 = blockIdx.x * 32, n0 = blockIdx.y * 32;
#pragma unroll
  for (int yy = ty; yy < 32; yy += 8)
    tile[yy][tx] = vb[(size_t)(k0 + yy) * 1024 + n0 + tx];
  __syncthreads();
#pragma unroll
  for (int yy = ty; yy < 32; yy += 8)
    vtb[(size_t)(n0 + yy) * 2048 + k0 + tx] = tile[tx][yy];
}

// ---------------- scores GEMM: Q[2048,1024] @ Mt[2048,1024]^T (x 1/1024) ----
// BM=256: grid 8 x 8 x 4 = 256 blocks (1 exact GPU round).
__global__ __launch_bounds__(512, 2) void score_gemm(
    const unsigned short* __restrict__ q, const unsigned short* __restrict__ mt,
    unsigned short* __restrict__ sc) {
  extern __shared__ char lds[];
  f32x4 acc[8][4];
  const int b = blockIdx.z;
  gemm_core8<256, 1024>(q + (size_t)b * SS * DD, mt + (size_t)b * SS * DD,
                        1024, 1024, blockIdx.y * 256, blockIdx.x * 256, lds, acc);
  unsigned short* out = sc + (size_t)b * SS * SS;
  const int lane = threadIdx.x & 63, w = threadIdx.x >> 6;
  const int wr = w >> 2, wc = w & 3;
  const int colb = blockIdx.x * 256 + wc * 64 + (lane & 15);
  const int rowb = blockIdx.y * 256 + wr * 128 + (lane >> 4) * 4;
  const float scale = 1.0f / 1024.0f;
#pragma unroll
  for (int f = 0; f < 8; ++f)
#pragma unroll
    for (int i = 0; i < 4; ++i) {
      const size_t rowoff = (size_t)(rowb + f * 16 + i) * 2048;
#pragma unroll
      for (int n = 0; n < 4; ++n)
        out[rowoff + colb + n * 16] = f2bf(acc[f][n][i] * scale);
    }
}

// ---------------- row softmax IN-PLACE: bf16 [8192][2048] ----------------
__global__ __launch_bounds__(256) void softmax_kernel(unsigned short* __restrict__ sc) {
  const size_t row = blockIdx.x;
  unsigned short* io = sc + row * 2048;
  const int t = threadIdx.x;
  ushort4 u0 = ((const ushort4*)io)[t];
  ushort4 u1 = ((const ushort4*)io)[t + 256];
  float v[8];
  v[0] = bf2f(u0.x); v[1] = bf2f(u0.y); v[2] = bf2f(u0.z); v[3] = bf2f(u0.w);
  v[4] = bf2f(u1.x); v[5] = bf2f(u1.y); v[6] = bf2f(u1.z); v[7] = bf2f(u1.w);
  float m = v[0];
#pragma unroll
  for (int j = 1; j < 8; ++j) m = fmaxf(m, v[j]);
#pragma unroll
  for (int off = 32; off > 0; off >>= 1) m = fmaxf(m, __shfl_xor(m, off));
  __shared__ float redm[4], reds[4];
  const int w = t >> 6;
  if ((t & 63) == 0) redm[w] = m;
  __syncthreads();
  m = fmaxf(fmaxf(redm[0], redm[1]), fmaxf(redm[2], redm[3]));
  float s = 0.f;
#pragma unroll
  for (int j = 0; j < 8; ++j) { v[j] = __expf(v[j] - m); s += v[j]; }
#pragma unroll
  for (int off = 32; off > 0; off >>= 1) s += __shfl_xor(s, off);
  if ((t & 63) == 0) reds[w] = s;
  __syncthreads();
  const float inv = 1.0f / (reds[0] + reds[1] + reds[2] + reds[3]);
  ushort4 o0, o1;
  o0.x = f2bf(v[0] * inv); o0.y = f2bf(v[1] * inv); o0.z = f2bf(v[2] * inv); o0.w = f2bf(v[3] * inv);
  o1.x = f2bf(v[4] * inv); o1.y = f2bf(v[5] * inv); o1.z = f2bf(v[6] * inv); o1.w = f2bf(v[7] * inv);
  ((ushort4*)io)[t] = o0;
  ((ushort4*)io)[t + 256] = o1;
}

// ---------------- PV GEMM: P[2048,2048] @ Vt[1024,2048]^T -> fp32 ----------
// BM=128: grid 4 x 16 x 4 = 256 blocks (1 exact GPU round).
__global__ __launch_bounds__(512, 2) void pv_gemm(
    const unsigned short* __restrict__ p, const unsigned short* __restrict__ vt,
    float* __restrict__ out) {
  extern __shared__ char lds[];
  f32x4 acc[4][4];
  const int b = blockIdx.z;
  gemm_core8<128, 2048>(p + (size_t)b * SS * SS, vt + (size_t)b * DD * SS,
                        2048, 2048, blockIdx.y * 128, blockIdx.x * 256, lds, acc);
  float* ob = out + (size_t)b * SS * DD;
  const int lane = threadIdx.x & 63, w = threadIdx.x >> 6;
  const int wr = w >> 2, wc = w & 3;
  const int colb = blockIdx.x * 256 + wc * 64 + (lane & 15);
  const int rowb = blockIdx.y * 128 + wr * 64 + (lane >> 4) * 4;
#pragma unroll
  for (int f = 0; f < 4; ++f)
#pragma unroll
    for (int i = 0; i < 4; ++i) {
      const size_t rowoff = (size_t)(rowb + f * 16 + i) * 1024;
#pragma unroll
      for (int n = 0; n < 4; ++n)
        ob[rowoff + colb + n * 16] = acc[f][n][i];
    }
}

extern "C" void kernel_launch(void* const* d_in, const int* in_sizes, int n_in,
                              void* d_out, int out_size, void* d_ws, size_t ws_size,
                              hipStream_t stream) {
  const float* x  = (const float*)d_in[0];
  const float* wq = (const float*)d_in[1];
  const float* wk = (const float*)d_in[2];
  const float* wv = (const float*)d_in[3];
  float* out = (float*)d_out;
  uint8_t* ws = (uint8_t*)d_ws;

  const size_t MB = 1u << 20;
  unsigned short* xb   = (unsigned short*)(ws);               // 16 MB  [8192][1024]
  unsigned short* wcat = (unsigned short*)(ws + 16 * MB);     //  6 MB  [3072][1024]
  unsigned short* q    = (unsigned short*)(ws + 22 * MB);     // 16 MB
  unsigned short* kk   = (unsigned short*)(ws + 38 * MB);     // 16 MB
  unsigned short* vv   = (unsigned short*)(ws + 54 * MB);     // 16 MB
  unsigned short* mt   = (unsigned short*)(ws + 70 * MB);     // 16 MB  [b][2048][1024]
  unsigned short* vt   = (unsigned short*)(ws + 86 * MB);     // 16 MB  [b][1024][2048]
  unsigned short* sc   = (unsigned short*)(ws + 102 * MB);    // 32 MB  [b][2048][2048] (softmax in-place)
                                                              // -> 134 MB total

  convert_x<<<2048, 256, 0, stream>>>(x, xb, BB * SS * DD / 4);
  convert_w<<<3 * DD * DD / 4 / 256, 256, 0, stream>>>(wq, wk, wv, wcat);
  proj_gemm<<<dim3(12, 64), 512, 96 * 1024, stream>>>(xb, wcat, q, kk, vv);
  k_to_mt<<<dim3(32, 32, 8), dim3(32, 8), 0, stream>>>(kk, mt);
  v_to_vt<<<dim3(64, 32, 4), dim3(32, 8), 0, stream>>>(vv, vt);
  score_gemm<<<dim3(8, 8, 4), 512, 128 * 1024, stream>>>(q, mt, sc);
  softmax_kernel<<<BB * SS, 256, 0, stream>>>(sc);
  pv_gemm<<<dim3(4, 16, 4), 512, 96 * 1024, stream>>>(sc, vt, out);
}

// Round 8
// 263.087 us; speedup vs baseline: 1.0452x; 1.0061x over previous
//
#include <hip/hip_runtime.h>
#include <hip/hip_bf16.h>
#include <stdint.h>

// Problem: B=4, S=2048, D=1024. fp32 in, fp32 out.
#define BB 4
#define SS 2048
#define DD 1024

typedef __attribute__((ext_vector_type(4))) float f32x4;
typedef __attribute__((ext_vector_type(8))) __bf16 bf16x8;

typedef const __attribute__((address_space(1))) void* gptr_t;
typedef __attribute__((address_space(3))) void* lptr_t;

__device__ __forceinline__ void load_lds16(const void* g, void* l) {
  __builtin_amdgcn_global_load_lds((gptr_t)g, (lptr_t)l, 16, 0, 0);
}

#define SBAR0() __builtin_amdgcn_sched_barrier(0)

__device__ __forceinline__ void wait_vm0() {
  asm volatile("s_waitcnt vmcnt(0)" ::: "memory");
}
__device__ __forceinline__ void wait_lgkm0() {
  asm volatile("s_waitcnt lgkmcnt(0)" ::: "memory");
}

__device__ __forceinline__ unsigned short f2bf(float x) {
  union { float f; uint32_t u; } v; v.f = x;
  uint32_t u = v.u;
  return (unsigned short)((u + 0x7FFFu + ((u >> 16) & 1u)) >> 16); // RNE
}
__device__ __forceinline__ float bf2f(unsigned short h) {
  union { uint32_t u; float f; } v; v.u = ((uint32_t)h) << 16; return v.f;
}

// ---------------- fp32 -> bf16 convert: x (grid-stride) ----------------
__global__ __launch_bounds__(256) void convert_x(
    const float* __restrict__ in, unsigned short* __restrict__ out, int n4) {
  for (int i = blockIdx.x * 256 + threadIdx.x; i < n4; i += gridDim.x * 256) {
    float4 v = ((const float4*)in)[i];
    ushort4 o;
    o.x = f2bf(v.x); o.y = f2bf(v.y); o.z = f2bf(v.z); o.w = f2bf(v.w);
    ((ushort4*)out)[i] = o;
  }
}

// ---------------- fp32 -> bf16 convert: the 3 weight matrices ----------------
__global__ __launch_bounds__(256) void convert_w(
    const float* __restrict__ wq, const float* __restrict__ wk,
    const float* __restrict__ wv, unsigned short* __restrict__ wcat) {
  const int n4 = DD * DD / 4;
  int i = blockIdx.x * 256 + threadIdx.x;
  const int which = i / n4, j = i - which * n4;
  const float* src = (which == 0) ? wq : ((which == 1) ? wk : wv);
  float4 v = ((const float4*)src)[j];
  ushort4 o;
  o.x = f2bf(v.x); o.y = f2bf(v.y); o.z = f2bf(v.z); o.w = f2bf(v.w);
  ((ushort4*)(wcat + (size_t)which * DD * DD))[j] = o;
}

// ========== free-flow GEMM core, SAFE ledger (vmcnt0 -> barrier -> stage) =========
// C[BM x 256] = A[M,K] @ Bt[N,K]^T, bf16 MFMA 16x16x32, 512 thr = 8 waves (2Mx4N),
// wave tile (BM/2) x 64. BK=64, double-buffered LDS, PROVEN 128B-row layout with
// phys col16 = logical ^ (row&7) both-sides swizzle (0 conflicts measured r4/r6).
// Per K-tile t:
//   vmcnt(0)   -- my tile-t loads retired (issued a FULL tile ago -> ~free drain)
//   barrier    -- everyone's tile-t loads landed; also all tile t-1 ds_reads
//                 retired block-wide (each wave lgkm0's in its last phase)
//   stage(t+1) -- burst all chunks into buffer (t+1)&1; race-free: that
//                 buffer's readers (tile t-1) finished before this barrier
//   NPH phases, NO intra-tile barriers (free-flow; waves drift & overlap pipes):
//     {ds_read frags; lgkm0; sched_barrier; setprio(1); 16 MFMA; setprio(0)}
template <int BM, int KLEN>
__device__ __forceinline__ void gemm_coreF(
    const unsigned short* __restrict__ A, const unsigned short* __restrict__ Bt,
    int lda, int ldb, int row0, int col0, char* lds,
    f32x4 (&acc)[BM / 32][4]) {
  constexpr int M_REP = BM / 32;            // 4 or 8
  constexpr int NPH  = M_REP / 2;           // 2 or 4 phases (2 m-frags each)
  constexpr int NT   = KLEN / 64;
  constexpr int NCA  = BM / 64;             // A 8KB-chunks per buffer (2 or 4)
  constexpr int ASZ  = BM * 128;            // A bytes per buffer
  constexpr int BUF  = ASZ + 32768;         // + B (256 x 64 x 2B)

  const int tid = threadIdx.x, lane = tid & 63, w = tid >> 6;
  const int wr = w >> 2, wc = w & 3;
  const int l7 = lane & 7, l15 = lane & 15, l16 = lane >> 4;

#pragma unroll
  for (int m = 0; m < M_REP; ++m)
#pragma unroll
    for (int n = 0; n < 4; ++n) acc[m][n] = (f32x4)(0.f);

  // stage-side: 512 threads cover one 8KB chunk (64 rows x 128B) per instr.
  // thread -> row tid>>3, phys col16 tid&7; source col16 pre-swizzled.
  const int srow = tid >> 3;
  const int scol = (tid & 7) ^ (srow & 7);
  const unsigned short* sA = A  + (size_t)(row0 + srow) * lda + scol * 8;
  const unsigned short* sB = Bt + (size_t)(col0 + srow) * ldb + scol * 8;

  auto SA = [&](int t, int c) {
    load_lds16(sA + (size_t)c * 64 * lda + t * 64, lds + (t & 1) * BUF + c * 8192 + tid * 16);
  };
  auto SB = [&](int t, int c) {
    load_lds16(sB + (size_t)c * 64 * ldb + t * 64, lds + (t & 1) * BUF + ASZ + c * 8192 + tid * 16);
  };

  // read-side (swizzled): phys col16 = logical ^ (row&7), row&7 == lane&7
  const int xc0 = (l16 ^ l7) * 16;        // k-substep 0
  const int xc1 = ((4 + l16) ^ l7) * 16;  // k-substep 1
  const char* rA = lds + (wr * (BM / 2) + l15) * 128;
  const char* rB = lds + ASZ + (wc * 64 + l15) * 128;

  // prologue: tile 0, all chunks
#pragma unroll
  for (int c = 0; c < NCA; ++c) SA(0, c);
#pragma unroll
  for (int c = 0; c < 4; ++c) SB(0, c);

#pragma unroll 1
  for (int t = 0; t < NT; ++t) {
    // ---- safe entry: my tile-t loads retired; barrier -> ALL waves' landed ----
    wait_vm0();
    SBAR0();
    __builtin_amdgcn_s_barrier();
    SBAR0();
    // ---- burst-stage tile t+1 into the other buffer (full-tile lead) ----
    if (t + 1 < NT) {
#pragma unroll
      for (int c = 0; c < NCA; ++c) SA(t + 1, c);
#pragma unroll
      for (int c = 0; c < 4; ++c) SB(t + 1, c);
    }
    SBAR0();

    const char* pA = rA + (t & 1) * BUF;
    const char* pB = rB + (t & 1) * BUF;

    // B fragments for the whole tile (read once, phase 0)
    bf16x8 bfr[4][2];
#pragma unroll
    for (int n = 0; n < 4; ++n) {
      bfr[n][0] = *(const bf16x8*)(pB + n * 2048 + xc0);
      bfr[n][1] = *(const bf16x8*)(pB + n * 2048 + xc1);
    }

#pragma unroll
    for (int q = 0; q < NPH; ++q) {
      bf16x8 af[2][2];
#pragma unroll
      for (int i = 0; i < 2; ++i) {
        af[i][0] = *(const bf16x8*)(pA + (2 * q + i) * 2048 + xc0);
        af[i][1] = *(const bf16x8*)(pA + (2 * q + i) * 2048 + xc1);
      }
      wait_lgkm0();
      SBAR0();
      __builtin_amdgcn_s_setprio(1);
#pragma unroll
      for (int i = 0; i < 2; ++i)
#pragma unroll
        for (int n = 0; n < 4; ++n)
#pragma unroll
          for (int ks = 0; ks < 2; ++ks)
            acc[2 * q + i][n] =
                __builtin_amdgcn_mfma_f32_16x16x32_bf16(af[i][ks], bfr[n][ks], acc[2 * q + i][n], 0, 0, 0);
      __builtin_amdgcn_s_setprio(0);
    }
  }
}

// ---------------- projection GEMM: [8192,1024] @ Wcat[3072,1024]^T ----------
// BM=256, BN=256: grid 12 x 32 = 384 blocks.
__global__ __launch_bounds__(512, 2) void proj_gemm(
    const unsigned short* __restrict__ xb, const unsigned short* __restrict__ wcat,
    unsigned short* __restrict__ q, unsigned short* __restrict__ kk,
    unsigned short* __restrict__ vv) {
  extern __shared__ char lds[];
  f32x4 acc[8][4];
  const int bn = blockIdx.x, bm = blockIdx.y;
  gemm_coreF<256, 1024>(xb, wcat, 1024, 1024, bm * 256, bn * 256, lds, acc);

  const int lane = threadIdx.x & 63, w = threadIdx.x >> 6;
  const int wr = w >> 2, wc = w & 3;
  const int which = bn >> 2;  // 0:q 1:k 2:v
  unsigned short* dst = (which == 0) ? q : ((which == 1) ? kk : vv);
  const int colb = (bn & 3) * 256 + wc * 64 + (lane & 15);
  const int rowb = bm * 256 + wr * 128 + (lane >> 4) * 4;
#pragma unroll
  for (int f = 0; f < 8; ++f)
#pragma unroll
    for (int i = 0; i < 4; ++i) {
      const size_t rowoff = (size_t)(rowb + f * 16 + i) * 1024;
#pragma unroll
      for (int n = 0; n < 4; ++n)
        dst[rowoff + colb + n * 16] = f2bf(acc[f][n][i]);
    }
}

// ---------------- K -> Mt (reshape folded transpose) ----------------
// Mt[b][delta*1024 + j][i] = K[b][2i+delta][j]
__global__ __launch_bounds__(256) void k_to_mt(
    const unsigned short* __restrict__ k, unsigned short* __restrict__ mt) {
  const int z = blockIdx.z, b = z >> 1, delta = z & 1;
  const unsigned short* kb = k + (size_t)b * SS * DD + (size_t)delta * DD;
  unsigned short* mtb = mt + (size_t)b * SS * DD + (size_t)delta * DD * DD;
  __shared__ unsigned short tile[32][33];
  const int tx = threadIdx.x, ty = threadIdx.y;
  const int i0 = blockIdx.x * 32, j0 = blockIdx.y * 32;
#pragma unroll
  for (int yy = ty; yy < 32; yy += 8)
    tile[yy][tx] = kb[(size_t)(i0 + yy) * 2048 + j0 + tx];
  __syncthreads();
#pragma unroll
  for (int yy = ty; yy < 32; yy += 8)
    mtb[(size_t)(j0 + yy) * 1024 + i0 + tx] = tile[tx][yy];
}

// ---------------- V -> Vt ----------------
__global__ __launch_bounds__(256) void v_to_vt(
    const unsigned short* __restrict__ v, unsigned short* __restrict__ vt) {
  const int b = blockIdx.z;
  const unsigned short* vb = v + (size_t)b * SS * DD;
  unsigned short* vtb = vt + (size_t)b * DD * SS;
  __shared__ unsigned short tile[32][33];
  const int tx = threadIdx.x, ty = threadIdx.y;
  const int k0 = blockIdx.x * 32, n0 = blockIdx.y * 32;
#pragma unroll
  for (int yy = ty; yy < 32; yy += 8)
    tile[yy][tx] = vb[(size_t)(k0 + yy) * 1024 + n0 + tx];
  __syncthreads();
#pragma unroll
  for (int yy = ty; yy < 32; yy += 8)
    vtb[(size_t)(n0 + yy) * 2048 + k0 + tx] = tile[tx][yy];
}

// ---------------- scores GEMM: Q[2048,1024] @ Mt[2048,1024]^T (x 1/1024) ----
// BM=256: grid 8 x 8 x 4 = 256 blocks.
__global__ __launch_bounds__(512, 2) void score_gemm(
    const unsigned short* __restrict__ q, const unsigned short* __restrict__ mt,
    unsigned short* __restrict__ sc) {
  extern __shared__ char lds[];
  f32x4 acc[8][4];
  const int b = blockIdx.z;
  gemm_coreF<256, 1024>(q + (size_t)b * SS * DD, mt + (size_t)b * SS * DD,
                        1024, 1024, blockIdx.y * 256, blockIdx.x * 256, lds, acc);
  unsigned short* out = sc + (size_t)b * SS * SS;
  const int lane = threadIdx.x & 63, w = threadIdx.x >> 6;
  const int wr = w >> 2, wc = w & 3;
  const int colb = blockIdx.x * 256 + wc * 64 + (lane & 15);
  const int rowb = blockIdx.y * 256 + wr * 128 + (lane >> 4) * 4;
  const float scale = 1.0f / 1024.0f;
#pragma unroll
  for (int f = 0; f < 8; ++f)
#pragma unroll
    for (int i = 0; i < 4; ++i) {
      const size_t rowoff = (size_t)(rowb + f * 16 + i) * 2048;
#pragma unroll
      for (int n = 0; n < 4; ++n)
        out[rowoff + colb + n * 16] = f2bf(acc[f][n][i] * scale);
    }
}

// ---------------- row softmax IN-PLACE: bf16 [8192][2048] ----------------
__global__ __launch_bounds__(256) void softmax_kernel(unsigned short* __restrict__ sc) {
  const size_t row = blockIdx.x;
  unsigned short* io = sc + row * 2048;
  const int t = threadIdx.x;
  ushort4 u0 = ((const ushort4*)io)[t];
  ushort4 u1 = ((const ushort4*)io)[t + 256];
  float v[8];
  v[0] = bf2f(u0.x); v[1] = bf2f(u0.y); v[2] = bf2f(u0.z); v[3] = bf2f(u0.w);
  v[4] = bf2f(u1.x); v[5] = bf2f(u1.y); v[6] = bf2f(u1.z); v[7] = bf2f(u1.w);
  float m = v[0];
#pragma unroll
  for (int j = 1; j < 8; ++j) m = fmaxf(m, v[j]);
#pragma unroll
  for (int off = 32; off > 0; off >>= 1) m = fmaxf(m, __shfl_xor(m, off));
  __shared__ float redm[4], reds[4];
  const int w = t >> 6;
  if ((t & 63) == 0) redm[w] = m;
  __syncthreads();
  m = fmaxf(fmaxf(redm[0], redm[1]), fmaxf(redm[2], redm[3]));
  float s = 0.f;
#pragma unroll
  for (int j = 0; j < 8; ++j) { v[j] = __expf(v[j] - m); s += v[j]; }
#pragma unroll
  for (int off = 32; off > 0; off >>= 1) s += __shfl_xor(s, off);
  if ((t & 63) == 0) reds[w] = s;
  __syncthreads();
  const float inv = 1.0f / (reds[0] + reds[1] + reds[2] + reds[3]);
  ushort4 o0, o1;
  o0.x = f2bf(v[0] * inv); o0.y = f2bf(v[1] * inv); o0.z = f2bf(v[2] * inv); o0.w = f2bf(v[3] * inv);
  o1.x = f2bf(v[4] * inv); o1.y = f2bf(v[5] * inv); o1.z = f2bf(v[6] * inv); o1.w = f2bf(v[7] * inv);
  ((ushort4*)io)[t] = o0;
  ((ushort4*)io)[t + 256] = o1;
}

// ---------------- PV GEMM: P[2048,2048] @ Vt[1024,2048]^T -> fp32 ----------
// BM=128, BN=256: grid 4 x 16 x 4 = 256 blocks.
__global__ __launch_bounds__(512, 2) void pv_gemm(
    const unsigned short* __restrict__ p, const unsigned short* __restrict__ vt,
    float* __restrict__ out) {
  extern __shared__ char lds[];
  f32x4 acc[4][4];
  const int b = blockIdx.z;
  gemm_coreF<128, 2048>(p + (size_t)b * SS * SS, vt + (size_t)b * DD * SS,
                        2048, 2048, blockIdx.y * 128, blockIdx.x * 256, lds, acc);
  float* ob = out + (size_t)b * SS * DD;
  const int lane = threadIdx.x & 63, w = threadIdx.x >> 6;
  const int wr = w >> 2, wc = w & 3;
  const int colb = blockIdx.x * 256 + wc * 64 + (lane & 15);
  const int rowb = blockIdx.y * 128 + wr * 64 + (lane >> 4) * 4;
#pragma unroll
  for (int f = 0; f < 4; ++f)
#pragma unroll
    for (int i = 0; i < 4; ++i) {
      const size_t rowoff = (size_t)(rowb + f * 16 + i) * 1024;
#pragma unroll
      for (int n = 0; n < 4; ++n)
        ob[rowoff + colb + n * 16] = acc[f][n][i];
    }
}

extern "C" void kernel_launch(void* const* d_in, const int* in_sizes, int n_in,
                              void* d_out, int out_size, void* d_ws, size_t ws_size,
                              hipStream_t stream) {
  const float* x  = (const float*)d_in[0];
  const float* wq = (const float*)d_in[1];
  const float* wk = (const float*)d_in[2];
  const float* wv = (const float*)d_in[3];
  float* out = (float*)d_out;
  uint8_t* ws = (uint8_t*)d_ws;

  const size_t MB = 1u << 20;
  unsigned short* xb   = (unsigned short*)(ws);               // 16 MB  [8192][1024]
  unsigned short* wcat = (unsigned short*)(ws + 16 * MB);     //  6 MB  [3072][1024]
  unsigned short* q    = (unsigned short*)(ws + 22 * MB);     // 16 MB
  unsigned short* kk   = (unsigned short*)(ws + 38 * MB);     // 16 MB
  unsigned short* vv   = (unsigned short*)(ws + 54 * MB);     // 16 MB
  unsigned short* mt   = (unsigned short*)(ws + 70 * MB);     // 16 MB  [b][2048][1024]
  unsigned short* vt   = (unsigned short*)(ws + 86 * MB);     // 16 MB  [b][1024][2048]
  unsigned short* sc   = (unsigned short*)(ws + 102 * MB);    // 32 MB  (softmax in-place)

  convert_x<<<2048, 256, 0, stream>>>(x, xb, BB * SS * DD / 4);
  convert_w<<<3 * DD * DD / 4 / 256, 256, 0, stream>>>(wq, wk, wv, wcat);
  proj_gemm<<<dim3(12, 32), 512, 128 * 1024, stream>>>(xb, wcat, q, kk, vv);
  k_to_mt<<<dim3(32, 32, 8), dim3(32, 8), 0, stream>>>(kk, mt);
  v_to_vt<<<dim3(64, 32, 4), dim3(32, 8), 0, stream>>>(vv, vt);
  score_gemm<<<dim3(8, 8, 4), 512, 128 * 1024, stream>>>(q, mt, sc);
  softmax_kernel<<<BB * SS, 256, 0, stream>>>(sc);
  pv_gemm<<<dim3(4, 16, 4), 512, 96 * 1024, stream>>>(sc, vt, out);
}